// Round 5
// baseline (3817.057 us; speedup 1.0000x reference)
//
#include <hip/hip_runtime.h>
#include <cstdint>
#include <cstddef>

// SNN forward, fp32-faithful to the reference's arithmetic (PASSING r4 semantics):
//  - state (v,i) fp32, strict __fmul_rn/__fadd_rn (no FMA contraction)
//  - reductions: sequential ascending-k __fmaf_rn, acc starts 0, bias AFTER
//  - conv2 k-order (ic,kr,kc); x10 after bias; spike (vd-1)>0
//  - zero-term skipping bitwise-exact (fmaf(w,0,acc)==acc)
// Round 5 delta: FULL UNROLL of all constant-trip loops so per-thread arrays
// live in registers (r4 spilled to scratch: 410 MB HBM writeback, VALUBusy 20%).
// Unrolling preserves arithmetic order exactly.

#define TSTEPS 64
#define NB 256

__global__ __launch_bounds__(256)
void transpose_wfc(const float* __restrict__ wfc, float* __restrict__ wfcT) {
    int idx = blockIdx.x * 256 + threadIdx.x;     // [500,800] -> [800,500]
    if (idx < 500 * 800) {
        int o = idx / 800, j = idx % 800;
        wfcT[j * 500 + o] = wfc[idx];
    }
}

__global__ __launch_bounds__(512, 2)
void snn_forward(const float* __restrict__ x,      // [64,256,1,28,28]
                 const float* __restrict__ w1,     // [20,1,5,5]
                 const float* __restrict__ b1,     // [20]
                 const float* __restrict__ w2,     // [50,20,5,5]
                 const float* __restrict__ b2,     // [50]
                 const float* __restrict__ fcw,    // wfcT [800,500] (sj=500,so=1) or wfc [500,800]
                 long fc_sj, long fc_so,
                 const float* __restrict__ bfc,    // [500]
                 const float* __restrict__ wout,   // [10,500]
                 float* __restrict__ out)          // [64,256,10]
{
    const float CM = 0.1f;
    const float CS = 0.8f;

    const int b   = blockIdx.x;
    const int tid = threadIdx.x;

    // ---- LDS (~23 KB) ----
    __shared__ float xs[28 * 36];                    // input tile, row stride 36
    __shared__ float p1[20 * 12 * 12];               // pooled L1 spikes, 0.0/1.0
    __shared__ unsigned char flag1[240];             // [20][12] row-has-spike
    __shared__ unsigned char s2s[3200];              // L2 spike map [50][8][8]
    __shared__ unsigned int  bm2[25];                // pooled-L2 bitmap (800 bits)
    __shared__ unsigned char s3[512];                // L3 spike map [500]
    __shared__ unsigned int  bm3[16];                // L3 bitmap
    __shared__ float v2s[500], i2s[500];             // L3 LIF state
    __shared__ float vos[10],  ios[10];              // output LI state

    if (tid < 500) { v2s[tid] = 0.f; i2s[tid] = 0.f; }
    if (tid < 10)  { vos[tid] = 0.f; ios[tid] = 0.f; }

    // ---- layer-1 mapping: 480 threads = 20 ch x 12 pool-rows x 2 col-halves ----
    const int l1  = (tid < 480);
    const int c   = tid / 24;
    const int sub = tid % 24;
    const int pr  = sub >> 1;
    const int chh = sub & 1;
    const int r0  = pr * 2;
    const int c0  = chh * 12;

    float w1r[25];
    float bias1 = 0.f;
    if (l1) {
        bias1 = b1[c];
        #pragma unroll
        for (int k = 0; k < 25; ++k) w1r[k] = w1[c * 25 + k];
    }
    float v0a[12], v0b[12], i0a[12], i0b[12];
    #pragma unroll
    for (int j = 0; j < 12; ++j) { v0a[j] = 0.f; v0b[j] = 0.f; i0a[j] = 0.f; i0b[j] = 0.f; }

    // ---- layer-2 mapping: 400 threads = 50 oc x 8 out-rows; thread owns 8 cols ----
    const int l2  = (tid < 400);
    const int oc2 = tid >> 3;
    const int y2  = tid & 7;
    float v1r[8], i1r[8];
    #pragma unroll
    for (int j = 0; j < 8; ++j) { v1r[j] = 0.f; i1r[j] = 0.f; }
    const float bias2 = l2 ? b2[oc2] : 0.f;

    for (int ts = 0; ts < TSTEPS; ++ts) {
        if (tid < 240) flag1[tid] = 0;
        const float* xp = x + ((size_t)ts * NB + b) * 784;
        #pragma unroll
        for (int ii = 0; ii < 2; ++ii) {
            int i = tid + ii * 512;
            if (i < 784) {
                int r = i / 28, cc = i - r * 28;
                xs[r * 36 + cc] = xp[i];
            }
        }
        __syncthreads();   // (A)

        // ========== conv1 (fma, (kr,kc) asc, bias AFTER) + LIF1 + pool1 ==========
        if (l1) {
            float acc0[12], acc1[12];
            #pragma unroll
            for (int j = 0; j < 12; ++j) { acc0[j] = 0.f; acc1[j] = 0.f; }
            #pragma unroll
            for (int ir = 0; ir < 6; ++ir) {
                float xr[16];
                const float* rp = xs + (r0 + ir) * 36 + c0;
                #pragma unroll
                for (int q = 0; q < 16; ++q) xr[q] = rp[q];
                if (ir < 5) {                      // out row r0, kr = ir
                    #pragma unroll
                    for (int kc = 0; kc < 5; ++kc) {
                        const float w = w1r[ir * 5 + kc];
                        #pragma unroll
                        for (int j = 0; j < 12; ++j)
                            acc0[j] = __fmaf_rn(w, xr[j + kc], acc0[j]);
                    }
                }
                if (ir >= 1) {                     // out row r0+1, kr = ir-1
                    #pragma unroll
                    for (int kc = 0; kc < 5; ++kc) {
                        const float w = w1r[(ir - 1) * 5 + kc];
                        #pragma unroll
                        for (int j = 0; j < 12; ++j)
                            acc1[j] = __fmaf_rn(w, xr[j + kc], acc1[j]);
                    }
                }
            }
            unsigned int zb0 = 0, zb1 = 0;
            #pragma unroll
            for (int j = 0; j < 12; ++j) {
                const float inp = __fadd_rn(acc0[j], bias1);
                const float vd  = __fadd_rn(v0a[j], __fmul_rn(CM, __fsub_rn(i0a[j], v0a[j])));
                const float id  = __fmul_rn(i0a[j], CS);
                const int z = (__fsub_rn(vd, 1.0f) > 0.0f);
                v0a[j] = z ? 0.f : vd;
                i0a[j] = __fadd_rn(id, inp);
                zb0 |= (unsigned)z << j;
            }
            #pragma unroll
            for (int j = 0; j < 12; ++j) {
                const float inp = __fadd_rn(acc1[j], bias1);
                const float vd  = __fadd_rn(v0b[j], __fmul_rn(CM, __fsub_rn(i0b[j], v0b[j])));
                const float id  = __fmul_rn(i0b[j], CS);
                const int z = (__fsub_rn(vd, 1.0f) > 0.0f);
                v0b[j] = z ? 0.f : vd;
                i0b[j] = __fadd_rn(id, inp);
                zb1 |= (unsigned)z << j;
            }
            const unsigned int zp = zb0 | zb1;
            #pragma unroll
            for (int jj = 0; jj < 6; ++jj)
                p1[(c * 12 + pr) * 12 + chh * 6 + jj] = ((zp >> (2 * jj)) & 3u) ? 1.0f : 0.0f;
            if (zp) flag1[c * 12 + pr] = 1;
        }
        __syncthreads();   // (B)

        // ========== conv2 (fma, (ic,kr,kc) asc, bias AFTER, x10 AFTER) + LIF2 ==========
        if (l2) {
            float acc[8];
            #pragma unroll
            for (int xx = 0; xx < 8; ++xx) acc[xx] = 0.f;
            for (int ic = 0; ic < 20; ++ic) {       // rolled: keeps I-cache small
                #pragma unroll
                for (int kr = 0; kr < 5; ++kr) {
                    const int py = y2 + kr;
                    if (!flag1[ic * 12 + py]) continue;   // exact: all terms zero
                    const float* prow = p1 + (ic * 12 + py) * 12;
                    const float* wrow = w2 + ((oc2 * 20 + ic) * 5 + kr) * 5;
                    float pv[12];
                    #pragma unroll
                    for (int q = 0; q < 12; ++q) pv[q] = prow[q];
                    #pragma unroll
                    for (int kc = 0; kc < 5; ++kc) {
                        const float w = wrow[kc];
                        #pragma unroll
                        for (int xx = 0; xx < 8; ++xx)
                            acc[xx] = __fmaf_rn(w, pv[xx + kc], acc[xx]);
                    }
                }
            }
            unsigned long long zm = 0ull;
            #pragma unroll
            for (int xx = 0; xx < 8; ++xx) {
                const float inp = __fmul_rn(10.0f, __fadd_rn(acc[xx], bias2));
                const float vd  = __fadd_rn(v1r[xx], __fmul_rn(CM, __fsub_rn(i1r[xx], v1r[xx])));
                const float id  = __fmul_rn(i1r[xx], CS);
                const int z = (__fsub_rn(vd, 1.0f) > 0.0f);
                v1r[xx] = z ? 0.f : vd;
                i1r[xx] = __fadd_rn(id, inp);
                zm |= (unsigned long long)z << (8 * xx);
            }
            ((unsigned long long*)s2s)[tid] = zm;
        }
        __syncthreads();   // (C)

        // ========== pool2 -> bitmap ==========
        if (tid < 25) {
            unsigned int bits = 0;
            #pragma unroll
            for (int bb = 0; bb < 32; ++bb) {
                const int u  = tid * 32 + bb;
                const int oc = u >> 4;
                const int py = (u >> 2) & 3;
                const int px = u & 3;
                const int base = oc * 64 + py * 16 + px * 2;
                if (s2s[base] | s2s[base + 1] | s2s[base + 8] | s2s[base + 9])
                    bits |= 1u << bb;
            }
            bm2[tid] = bits;
        }
        __syncthreads();   // (D)

        // ========== fc 800->500 (fma, j asc, bias AFTER) + LIF3 ==========
        if (tid < 500) {
            float acc = 0.f;
            for (int w = 0; w < 25; ++w) {
                unsigned int bits = bm2[w];
                while (bits) {
                    const int bb = __builtin_ctz(bits);
                    bits &= bits - 1;
                    const long j = (long)(w * 32 + bb);
                    acc = __fmaf_rn(1.0f, fcw[j * fc_sj + (long)tid * fc_so], acc);
                }
            }
            const float inp = __fadd_rn(acc, bfc[tid]);
            const float vd  = __fadd_rn(v2s[tid], __fmul_rn(CM, __fsub_rn(i2s[tid], v2s[tid])));
            const float id  = __fmul_rn(i2s[tid], CS);
            const int z = (__fsub_rn(vd, 1.0f) > 0.0f);
            v2s[tid] = z ? 0.f : vd;
            i2s[tid] = __fadd_rn(id, inp);
            s3[tid] = (unsigned char)z;
        }
        __syncthreads();   // (E)

        // ========== L3 spike bitmap ==========
        if (tid < 16) {
            unsigned int bits = 0;
            #pragma unroll
            for (int bb = 0; bb < 32; ++bb) {
                const int j = tid * 32 + bb;
                if (j < 500 && s3[j]) bits |= 1u << bb;
            }
            bm3[tid] = bits;
        }
        __syncthreads();   // (F)

        // ========== output LI cell (strict) ==========
        if (tid < 10) {
            float acc = 0.f;
            for (int w = 0; w < 16; ++w) {
                unsigned int bits = bm3[w];
                while (bits) {
                    const int bb = __builtin_ctz(bits);
                    bits &= bits - 1;
                    acc = __fmaf_rn(1.0f, wout[tid * 500 + (w * 32 + bb)], acc);
                }
            }
            const float vn = __fadd_rn(vos[tid], __fmul_rn(CM, __fsub_rn(ios[tid], vos[tid])));
            ios[tid] = __fadd_rn(__fmul_rn(ios[tid], CS), acc);
            vos[tid] = vn;
            out[((size_t)ts * NB + b) * 10 + tid] = vn;
        }
        __syncthreads();   // (G)
    }
}

extern "C" void kernel_launch(void* const* d_in, const int* in_sizes, int n_in,
                              void* d_out, int out_size, void* d_ws, size_t ws_size,
                              hipStream_t stream)
{
    const float* x    = (const float*)d_in[0];
    const float* w1   = (const float*)d_in[1];
    const float* b1   = (const float*)d_in[2];
    const float* w2   = (const float*)d_in[3];
    const float* b2   = (const float*)d_in[4];
    const float* wfc  = (const float*)d_in[5];
    const float* bfc  = (const float*)d_in[6];
    const float* wout = (const float*)d_in[7];
    float* out = (float*)d_out;

    const float* fcptr = wfc;
    long sj = 1, so = 800;
    if (ws_size >= (size_t)500 * 800 * sizeof(float)) {
        float* wfcT = (float*)d_ws;
        transpose_wfc<<<(500 * 800 + 255) / 256, 256, 0, stream>>>(wfc, wfcT);
        fcptr = wfcT; sj = 500; so = 1;
    }

    snn_forward<<<NB, 512, 0, stream>>>(x, w1, b1, w2, b2, fcptr, sj, so, bfc, wout, out);
}

// Round 6
// 2220.049 us; speedup vs baseline: 1.7194x; 1.7194x over previous
//
#include <hip/hip_runtime.h>
#include <cstdint>
#include <cstddef>

// SNN forward, fp32-faithful (r4/r5 passing semantics, bitwise-identical order):
//  - strict __fmul_rn/__fadd_rn LIF, ascending-k __fmaf_rn reductions, bias AFTER
//  - conv2 k-order (ic,kr,kc); x10 after bias; spike (vd-1)>0
//  - zero-term skipping bitwise-exact
// Round 6 deltas (perf only, order-preserving):
//  - w1 + layer-2 LIF state moved to LDS -> peak VGPR ~110 (<128) -> no scratch spills
//  - sparse stages use deterministic index lists (popcount prefix scan, ascending)
//    so loads batch 4-8 deep instead of one dependent load per spike
//  - conv2 row flags as per-ic 12-bit masks in registers (no per-flag LDS loads)
//  - xs double-buffered; next step's x prefetched during conv1

#define TSTEPS 64
#define NB 256

__global__ __launch_bounds__(256)
void transpose_wfc(const float* __restrict__ wfc, float* __restrict__ wfcT) {
    int idx = blockIdx.x * 256 + threadIdx.x;     // [500,800] -> [800,500]
    if (idx < 500 * 800) {
        int o = idx / 800, j = idx % 800;
        wfcT[j * 500 + o] = wfc[idx];
    }
}

__global__ __launch_bounds__(512, 2)
void snn_forward(const float* __restrict__ x,      // [64,256,1,28,28]
                 const float* __restrict__ w1,     // [20,1,5,5]
                 const float* __restrict__ b1,     // [20]
                 const float* __restrict__ w2,     // [50,20,5,5]
                 const float* __restrict__ b2,     // [50]
                 const float* __restrict__ fcw,    // wfcT [800,500] (sj=500,so=1) or wfc [500,800]
                 long fc_sj, long fc_so,
                 const float* __restrict__ bfc,    // [500]
                 const float* __restrict__ wout,   // [10,500]
                 float* __restrict__ out)          // [64,256,10]
{
    const float CM = 0.1f;
    const float CS = 0.8f;

    const int b   = blockIdx.x;
    const int tid = threadIdx.x;

    // ---- LDS (~53 KB) ----
    __shared__ float xs[2][28 * 36];                 // double-buffered input tile
    __shared__ float p1[20 * 12 * 12];               // pooled L1 spikes, 0.0/1.0
    __shared__ float w1L[500];                       // conv1 weights
    __shared__ unsigned int flagbits[20];            // 12 pooled-row flags per ic
    __shared__ unsigned int bm2[25];                 // pooled-L2 bitmap (800 bits)
    __shared__ unsigned int bm3[16];                 // L3 bitmap (500 bits)
    __shared__ int off2[25], off3[16];               // prefix offsets
    __shared__ unsigned short list2s[800];           // active fc-input indices (asc)
    __shared__ unsigned short list3s[512];           // active L3 indices (asc)
    __shared__ float v1L[8 * 400], i1L[8 * 400];     // L2 LIF state, plane [xx][tid]
    __shared__ float v2s[500], i2s[500];             // L3 LIF state
    __shared__ float vos[10],  ios[10];              // output LI state
    __shared__ int nn2s, nn3s;

    // ---- one-time init ----
    if (tid < 500) { v2s[tid] = 0.f; i2s[tid] = 0.f; w1L[tid] = w1[tid]; }
    if (tid < 10)  { vos[tid] = 0.f; ios[tid] = 0.f; }
    for (int i = tid; i < 3200; i += 512) { v1L[i] = 0.f; i1L[i] = 0.f; }

    // staging index map (constant per thread)
    const int sr0 = tid / 28,         sc0_ = tid - sr0 * 28;           // elem tid
    const int has2 = (tid + 512) < 784;
    const int sr1 = (tid + 512) / 28, sc1_ = (tid + 512) - sr1 * 28;   // elem tid+512

    // prologue: stage ts=0
    {
        const float* xp = x + ((size_t)b) * 784;     // ts=0
        xs[0][sr0 * 36 + sc0_] = xp[tid];
        if (has2) xs[0][sr1 * 36 + sc1_] = xp[tid + 512];
    }

    // ---- layer-1 mapping: 480 threads = 20 ch x 12 pool-rows x 2 col-halves ----
    const int l1  = (tid < 480);
    const int c   = tid / 24;
    const int sub = tid % 24;
    const int pr  = sub >> 1;
    const int chh = sub & 1;
    const int r0  = pr * 2;
    const int c0  = chh * 12;

    float v0a[12], v0b[12], i0a[12], i0b[12];        // L1 state (registers, 48)
    #pragma unroll
    for (int j = 0; j < 12; ++j) { v0a[j] = 0.f; v0b[j] = 0.f; i0a[j] = 0.f; i0b[j] = 0.f; }

    // ---- layer-2 mapping: 400 threads = 50 oc x 8 out-rows; 8 cols each ----
    const int l2  = (tid < 400);
    const int oc2 = tid >> 3;
    const int y2  = tid & 7;
    const float bias2 = l2 ? b2[oc2] : 0.f;
    const float bias1 = l1 ? b1[c] : 0.f;

    for (int ts = 0; ts < TSTEPS; ++ts) {
        const int cur = ts & 1, nxt = cur ^ 1;
        // reset bitmaps (prev step's users finished at barrier I)
        if (tid < 25) bm2[tid] = 0u;
        if (tid < 20) flagbits[tid] = 0u;
        if (tid < 16) bm3[tid] = 0u;
        __syncthreads();   // (A) xs[cur] ready, bitmaps zeroed

        // prefetch next step's x into registers (latency overlaps conv1)
        float xpre0 = 0.f, xpre1 = 0.f;
        if (ts + 1 < TSTEPS) {
            const float* xpn = x + ((size_t)(ts + 1) * NB + b) * 784;
            xpre0 = xpn[tid];
            if (has2) xpre1 = xpn[tid + 512];
        }

        // ========== conv1 (fma, (kr,kc) asc, bias AFTER) + LIF1 + pool1 ==========
        if (l1) {
            float acc0[12], acc1[12];
            #pragma unroll
            for (int j = 0; j < 12; ++j) { acc0[j] = 0.f; acc1[j] = 0.f; }
            float wc[5], wp[5];
            #pragma unroll
            for (int ir = 0; ir < 6; ++ir) {
                float xr[16];
                const float4* rp = (const float4*)(xs[cur] + (r0 + ir) * 36 + c0);
                #pragma unroll
                for (int q = 0; q < 4; ++q) {
                    float4 f = rp[q];
                    xr[4*q+0] = f.x; xr[4*q+1] = f.y; xr[4*q+2] = f.z; xr[4*q+3] = f.w;
                }
                if (ir < 5) {                      // rolling weight window (same values/order)
                    #pragma unroll
                    for (int k = 0; k < 5; ++k) wc[k] = w1L[c * 25 + ir * 5 + k];
                    #pragma unroll
                    for (int kc = 0; kc < 5; ++kc) {
                        const float w = wc[kc];
                        #pragma unroll
                        for (int j = 0; j < 12; ++j)
                            acc0[j] = __fmaf_rn(w, xr[j + kc], acc0[j]);
                    }
                }
                if (ir >= 1) {                     // out row r0+1, kr = ir-1 -> wp
                    #pragma unroll
                    for (int kc = 0; kc < 5; ++kc) {
                        const float w = wp[kc];
                        #pragma unroll
                        for (int j = 0; j < 12; ++j)
                            acc1[j] = __fmaf_rn(w, xr[j + kc], acc1[j]);
                    }
                }
                #pragma unroll
                for (int k = 0; k < 5; ++k) wp[k] = wc[k];
            }
            unsigned int zb0 = 0, zb1 = 0;
            #pragma unroll
            for (int j = 0; j < 12; ++j) {
                const float inp = __fadd_rn(acc0[j], bias1);
                const float vd  = __fadd_rn(v0a[j], __fmul_rn(CM, __fsub_rn(i0a[j], v0a[j])));
                const float id  = __fmul_rn(i0a[j], CS);
                const int z = (__fsub_rn(vd, 1.0f) > 0.0f);
                v0a[j] = z ? 0.f : vd;
                i0a[j] = __fadd_rn(id, inp);
                zb0 |= (unsigned)z << j;
            }
            #pragma unroll
            for (int j = 0; j < 12; ++j) {
                const float inp = __fadd_rn(acc1[j], bias1);
                const float vd  = __fadd_rn(v0b[j], __fmul_rn(CM, __fsub_rn(i0b[j], v0b[j])));
                const float id  = __fmul_rn(i0b[j], CS);
                const int z = (__fsub_rn(vd, 1.0f) > 0.0f);
                v0b[j] = z ? 0.f : vd;
                i0b[j] = __fadd_rn(id, inp);
                zb1 |= (unsigned)z << j;
            }
            const unsigned int zp = zb0 | zb1;
            #pragma unroll
            for (int jj = 0; jj < 6; ++jj)
                p1[(c * 12 + pr) * 12 + chh * 6 + jj] = ((zp >> (2 * jj)) & 3u) ? 1.0f : 0.0f;
            if (zp) atomicOr(&flagbits[c], 1u << pr);
        }
        // write prefetched x to the other buffer (read next step after barrier A)
        if (ts + 1 < TSTEPS) {
            xs[nxt][sr0 * 36 + sc0_] = xpre0;
            if (has2) xs[nxt][sr1 * 36 + sc1_] = xpre1;
        }
        __syncthreads();   // (B) p1, flagbits ready

        // ========== conv2 (fma, (ic,kr,kc) asc, bias AFTER, x10 AFTER) + LIF2 ==========
        if (l2) {
            float acc[8];
            #pragma unroll
            for (int xx = 0; xx < 8; ++xx) acc[xx] = 0.f;
            for (int ic = 0; ic < 20; ++ic) {
                const unsigned int win = (flagbits[ic] >> y2) & 31u;   // 5-row window mask
                if (!win) continue;                                     // all-zero: exact skip
                #pragma unroll
                for (int kr = 0; kr < 5; ++kr) {
                    if (!(win & (1u << kr))) continue;                  // exact skip
                    const float4* pp = (const float4*)(p1 + (ic * 12 + y2 + kr) * 12);
                    float4 f0 = pp[0], f1 = pp[1], f2 = pp[2];
                    const float pv[12] = { f0.x,f0.y,f0.z,f0.w, f1.x,f1.y,f1.z,f1.w, f2.x,f2.y,f2.z,f2.w };
                    const float* wrow = w2 + ((oc2 * 20 + ic) * 5 + kr) * 5;
                    const float w0 = wrow[0], w1_ = wrow[1], w2_ = wrow[2], w3_ = wrow[3], w4_ = wrow[4];
                    #pragma unroll
                    for (int xx = 0; xx < 8; ++xx) acc[xx] = __fmaf_rn(w0, pv[xx],     acc[xx]);
                    #pragma unroll
                    for (int xx = 0; xx < 8; ++xx) acc[xx] = __fmaf_rn(w1_, pv[xx + 1], acc[xx]);
                    #pragma unroll
                    for (int xx = 0; xx < 8; ++xx) acc[xx] = __fmaf_rn(w2_, pv[xx + 2], acc[xx]);
                    #pragma unroll
                    for (int xx = 0; xx < 8; ++xx) acc[xx] = __fmaf_rn(w3_, pv[xx + 3], acc[xx]);
                    #pragma unroll
                    for (int xx = 0; xx < 8; ++xx) acc[xx] = __fmaf_rn(w4_, pv[xx + 4], acc[xx]);
                }
            }
            unsigned int pb = 0;                                        // pooled bits for bm2
            const unsigned int bitbase = (unsigned)((oc2 & 1) * 16 + (y2 >> 1) * 4);
            #pragma unroll
            for (int xx = 0; xx < 8; ++xx) {
                const float vold = v1L[xx * 400 + tid];
                const float iold = i1L[xx * 400 + tid];
                const float inp  = __fmul_rn(10.0f, __fadd_rn(acc[xx], bias2));
                const float vd   = __fadd_rn(vold, __fmul_rn(CM, __fsub_rn(iold, vold)));
                const float id   = __fmul_rn(iold, CS);
                const int z = (__fsub_rn(vd, 1.0f) > 0.0f);
                v1L[xx * 400 + tid] = z ? 0.f : vd;
                i1L[xx * 400 + tid] = __fadd_rn(id, inp);
                if (z) pb |= 1u << (bitbase + (xx >> 1));
            }
            if (pb) atomicOr(&bm2[oc2 >> 1], pb);
        }
        __syncthreads();   // (C) bm2 complete

        if (tid == 0) {                                   // prefix scan (25 words)
            int off = 0;
            #pragma unroll
            for (int w = 0; w < 25; ++w) { off2[w] = off; off += __popc(bm2[w]); }
            nn2s = off;
        }
        __syncthreads();   // (D)
        if (tid < 25) {                                   // write ascending index list
            unsigned int bits = bm2[tid];
            int o = off2[tid];
            while (bits) {
                const int bb = __builtin_ctz(bits);
                bits &= bits - 1;
                list2s[o++] = (unsigned short)(tid * 32 + bb);
            }
        }
        __syncthreads();   // (E) list2s ready

        // ========== fc 800->500 (fma, j asc, bias AFTER) + LIF3 ==========
        if (tid < 500) {
            const int nn2 = nn2s;
            float acc = 0.f;
            int k = 0;
            for (; k + 7 < nn2; k += 8) {                 // 8 independent loads in flight
                const long j0 = list2s[k],     j1 = list2s[k + 1];
                const long j2 = list2s[k + 2], j3 = list2s[k + 3];
                const long j4 = list2s[k + 4], j5 = list2s[k + 5];
                const long j6 = list2s[k + 6], j7 = list2s[k + 7];
                const float a0 = fcw[j0 * fc_sj + (long)tid * fc_so];
                const float a1 = fcw[j1 * fc_sj + (long)tid * fc_so];
                const float a2 = fcw[j2 * fc_sj + (long)tid * fc_so];
                const float a3 = fcw[j3 * fc_sj + (long)tid * fc_so];
                const float a4 = fcw[j4 * fc_sj + (long)tid * fc_so];
                const float a5 = fcw[j5 * fc_sj + (long)tid * fc_so];
                const float a6 = fcw[j6 * fc_sj + (long)tid * fc_so];
                const float a7 = fcw[j7 * fc_sj + (long)tid * fc_so];
                acc = __fmaf_rn(1.0f, a0, acc); acc = __fmaf_rn(1.0f, a1, acc);
                acc = __fmaf_rn(1.0f, a2, acc); acc = __fmaf_rn(1.0f, a3, acc);
                acc = __fmaf_rn(1.0f, a4, acc); acc = __fmaf_rn(1.0f, a5, acc);
                acc = __fmaf_rn(1.0f, a6, acc); acc = __fmaf_rn(1.0f, a7, acc);
            }
            for (; k < nn2; ++k) {
                const long j = list2s[k];
                acc = __fmaf_rn(1.0f, fcw[j * fc_sj + (long)tid * fc_so], acc);
            }
            const float inp = __fadd_rn(acc, bfc[tid]);
            const float vd  = __fadd_rn(v2s[tid], __fmul_rn(CM, __fsub_rn(i2s[tid], v2s[tid])));
            const float id  = __fmul_rn(i2s[tid], CS);
            const int z = (__fsub_rn(vd, 1.0f) > 0.0f);
            v2s[tid] = z ? 0.f : vd;
            i2s[tid] = __fadd_rn(id, inp);
            if (z) atomicOr(&bm3[tid >> 5], 1u << (tid & 31));
        }
        __syncthreads();   // (F) bm3 complete

        if (tid == 0) {
            int off = 0;
            #pragma unroll
            for (int w = 0; w < 16; ++w) { off3[w] = off; off += __popc(bm3[w]); }
            nn3s = off;
        }
        __syncthreads();   // (G)
        if (tid < 16) {
            unsigned int bits = bm3[tid];
            int o = off3[tid];
            while (bits) {
                const int bb = __builtin_ctz(bits);
                bits &= bits - 1;
                list3s[o++] = (unsigned short)(tid * 32 + bb);
            }
        }
        __syncthreads();   // (H) list3s ready

        // ========== output LI cell (strict) ==========
        if (tid < 10) {
            const int nn3 = nn3s;
            float acc = 0.f;
            int k = 0;
            for (; k + 3 < nn3; k += 4) {
                const int j0 = list3s[k],     j1 = list3s[k + 1];
                const int j2 = list3s[k + 2], j3 = list3s[k + 3];
                const float a0 = wout[tid * 500 + j0];
                const float a1 = wout[tid * 500 + j1];
                const float a2 = wout[tid * 500 + j2];
                const float a3 = wout[tid * 500 + j3];
                acc = __fmaf_rn(1.0f, a0, acc); acc = __fmaf_rn(1.0f, a1, acc);
                acc = __fmaf_rn(1.0f, a2, acc); acc = __fmaf_rn(1.0f, a3, acc);
            }
            for (; k < nn3; ++k)
                acc = __fmaf_rn(1.0f, wout[tid * 500 + list3s[k]], acc);
            const float vn = __fadd_rn(vos[tid], __fmul_rn(CM, __fsub_rn(ios[tid], vos[tid])));
            ios[tid] = __fadd_rn(__fmul_rn(ios[tid], CS), acc);
            vos[tid] = vn;
            out[((size_t)ts * NB + b) * 10 + tid] = vn;
        }
        __syncthreads();   // (I) protect lists/LDS before next step's reset
    }
}

extern "C" void kernel_launch(void* const* d_in, const int* in_sizes, int n_in,
                              void* d_out, int out_size, void* d_ws, size_t ws_size,
                              hipStream_t stream)
{
    const float* x    = (const float*)d_in[0];
    const float* w1   = (const float*)d_in[1];
    const float* b1   = (const float*)d_in[2];
    const float* w2   = (const float*)d_in[3];
    const float* b2   = (const float*)d_in[4];
    const float* wfc  = (const float*)d_in[5];
    const float* bfc  = (const float*)d_in[6];
    const float* wout = (const float*)d_in[7];
    float* out = (float*)d_out;

    const float* fcptr = wfc;
    long sj = 1, so = 800;
    if (ws_size >= (size_t)500 * 800 * sizeof(float)) {
        float* wfcT = (float*)d_ws;
        transpose_wfc<<<(500 * 800 + 255) / 256, 256, 0, stream>>>(wfc, wfcT);
        fcptr = wfcT; sj = 500; so = 1;
    }

    snn_forward<<<NB, 512, 0, stream>>>(x, w1, b1, w2, b2, fcptr, sj, so, bfc, wout, out);
}